// Round 10
// baseline (251.510 us; speedup 1.0000x reference)
//
#include <hip/hip_runtime.h>
#include <hip/hip_bf16.h>
#include <math.h>

#define N_NODES 50000
#define N_EDGES 800000
#define IN_DIM  128
#define MEM_DIM 32
#define OUT_DIM 64
#define NB_SCAN ((N_NODES + 255) / 256)   // 196
#define SCALE   0.17677669529663687f      // 1/sqrt(32)
#define LOG2E   1.44269504088896f
#define INV2PI  0.15915494309189535f
#define LDS_AROW 168                      // padded A-tile row stride (elems)
#define NGB 625                           // GEMM blocks (5 tiles of 16 nodes each)

typedef __attribute__((ext_vector_type(8))) short bf16x8;
typedef __attribute__((ext_vector_type(4))) float f32x4;

__device__ __forceinline__ short f2bf(float f) {
    union { float f; unsigned u; } v; v.f = f;
    unsigned r = v.u + 0x7FFF + ((v.u >> 16) & 1);   // round-to-nearest-even
    return (short)(r >> 16);
}
__device__ __forceinline__ float lo16(unsigned u) { return __uint_as_float(u << 16); }
__device__ __forceinline__ float hi16(unsigned u) { return __uint_as_float(u & 0xffff0000u); }

// Cross-lane add via DPP (VALU pipe, not LDS). CTRL: 0xB1=quad_perm xor1,
// 0x4E=quad_perm xor2, 0x124=row_ror:4, 0x128=row_ror:8.
template <int CTRL>
__device__ __forceinline__ float dpp_mov(float x) {
    return __int_as_float(__builtin_amdgcn_update_dpp(
        0, __float_as_int(x), CTRL, 0xF, 0xF, true));
}
// xor16 within each 32-lane half (BitMode: xor=16, and=0x1F)
__device__ __forceinline__ float swz16(float x) {
    return __int_as_float(__builtin_amdgcn_ds_swizzle(__float_as_int(x), 0x401F));
}
// sum over the lane's 32-lane half: 4 DPP adds + 1 swizzle. Each 32-lane
// half reduces INDEPENDENTLY (one pass serves 2 records).
__device__ __forceinline__ float half_reduce(float pr) {
    pr += dpp_mov<0xB1>(pr);
    pr += dpp_mov<0x4E>(pr);
    pr += dpp_mov<0x124>(pr);
    pr += dpp_mov<0x128>(pr);
    pr += swz16(pr);
    return pr;
}
// cos(2*pi*x) via HW: v_fract + v_cos (args pre-scaled by 1/2pi)
__device__ __forceinline__ float cos_rev(float x) {
    return __builtin_amdgcn_cosf(__builtin_amdgcn_fractf(x));
}

// ---------------------------------------------------------------------------
// prep_k: bf16 weight bank in LANE-COALESCED B-frag layout (verified r5/r8).
// Also zeroes the 8-replica histogram.
// ---------------------------------------------------------------------------
__global__ __launch_bounds__(256) void prep_k(
    const float* __restrict__ Wq, const float* __restrict__ Wk,
    const float* __restrict__ Wv, const float* __restrict__ Wskip,
    const float* __restrict__ We_k, unsigned short* __restrict__ wtb,
    int* __restrict__ cntr)
{
    const int i = blockIdx.x * 256 + threadIdx.x;   // 1600*256 = 409600
    if (i < 8 * N_NODES) cntr[i] = 0;
    if (i >= 51200) return;                         // 5*64*160
    const int m = i / 10240, rem = i % 10240, c = rem / 160, k = rem % 160;
    float v;
    if (m == 4) {
        const int h = c >> 5, kk = c & 31;
        v = 0.f;
        #pragma unroll
        for (int j = 0; j < 32; ++j)
            v += Wq[k * 64 + h * 32 + j] * We_k[kk * 64 + h * 32 + j];
        v *= SCALE;
    } else {
        const float* W = (m == 0) ? Wq : (m == 1) ? Wk : (m == 2) ? Wv : Wskip;
        v = W[k * 64 + c];
        if (m == 0) v *= SCALE;
    }
    const int g = c >> 4, l15 = c & 15;
    const int kb = k >> 5, quad = (k >> 3) & 3, j = k & 7;
    wtb[(size_t)((((m * 5 + kb) * 4 + g) * 64) + quad * 16 + l15) * 8 + j] =
        (unsigned short)f2bf(v);
}

// ---------------------------------------------------------------------------
// node_gemm: PURE 5-tile node GEMM (verified r8/r9 body). zkv rows BY DIM:
//   zkv[row][d*4 + h + 2*isV]  -> agg lane d reads (k_h0,k_h1,v_h0,v_h1) 8B.
// ---------------------------------------------------------------------------
__global__ __launch_bounds__(320) void node_gemm(
    const float* __restrict__ x, const float* __restrict__ mem,
    const unsigned short* __restrict__ wtb,
    unsigned short* __restrict__ qq, unsigned short* __restrict__ zkv,
    float* __restrict__ out)
{
    const int tid = threadIdx.x;
    __shared__ unsigned short sA[16 * LDS_AROW];    // 5.25 KB bf16 in-tile
    __shared__ unsigned short sQQ[16 * 128];        // 4 KB
    __shared__ unsigned short sKV[16 * 128];        // 4 KB
    __shared__ float          sOUT[16 * 64];        // 4 KB

    const int w    = tid >> 6;                  // 0..4 (matrix id)
    const int lane = tid & 63;
    const int l15  = lane & 15;
    const int quad = lane >> 4;

    // ---- B-frags: once per block, fully coalesced (1KB per instruction) ----
    bf16x8 bfrag[5][4];
    #pragma unroll
    for (int kb = 0; kb < 5; ++kb)
        #pragma unroll
        for (int g = 0; g < 4; ++g)
            bfrag[kb][g] = *(const bf16x8*)(wtb +
                (size_t)(((w * 5 + kb) * 4 + g) * 64 + lane) * 8);

    // ---- fixed per-thread A-stage assignment (2 float4 each, 640 total) ----
    int nb = blockIdx.x * 80;
    const int r0 = tid >> 5, d0 = (tid & 31) * 4;
    const bool u1x = (tid < 192);
    const int i1 = tid + 320;
    const int r1 = u1x ? (i1 >> 5) : ((tid - 192) >> 3);
    const int d1 = u1x ? ((i1 & 31) * 4) : (((tid - 192) & 7) * 4);
    const float* p0 = x + (size_t)(nb + r0) * IN_DIM + d0;
    const float* p1 = u1x ? (x + (size_t)(nb + r1) * IN_DIM + d1)
                          : (mem + (size_t)(nb + r1) * MEM_DIM + d1);
    const int adv1 = u1x ? 16 * IN_DIM : 16 * MEM_DIM;
    unsigned short* s0 = sA + r0 * LDS_AROW + d0;
    unsigned short* s1 = sA + r1 * LDS_AROW + (u1x ? d1 : 128 + d1);

    // prologue: load tile 0
    float4 c0 = *(const float4*)p0; p0 += 16 * IN_DIM;
    float4 c1 = *(const float4*)p1; p1 += adv1;

    for (int t = 0; t < 5; ++t, nb += 16) {
        __syncthreads();                        // sA reusable
        s0[0] = (unsigned short)f2bf(c0.x); s0[1] = (unsigned short)f2bf(c0.y);
        s0[2] = (unsigned short)f2bf(c0.z); s0[3] = (unsigned short)f2bf(c0.w);
        s1[0] = (unsigned short)f2bf(c1.x); s1[1] = (unsigned short)f2bf(c1.y);
        s1[2] = (unsigned short)f2bf(c1.z); s1[3] = (unsigned short)f2bf(c1.w);
        __syncthreads();                        // A-tile visible

        if (t < 4) {                            // prefetch next tile
            c0 = *(const float4*)p0; p0 += 16 * IN_DIM;
            c1 = *(const float4*)p1; p1 += adv1;
        }

        f32x4 acc[4];
        #pragma unroll
        for (int g = 0; g < 4; ++g) acc[g] = (f32x4)0.0f;
        #pragma unroll
        for (int kb = 0; kb < 5; ++kb) {
            const bf16x8 afrag =
                *(const bf16x8*)(sA + l15 * LDS_AROW + kb * 32 + quad * 8);
            #pragma unroll
            for (int g = 0; g < 4; ++g)
                acc[g] = __builtin_amdgcn_mfma_f32_16x16x32_bf16(
                             afrag, bfrag[kb][g], acc[g], 0, 0, 0);
        }

        // ---- stage results into LDS out-tiles ----
        #pragma unroll
        for (int g = 0; g < 4; ++g) {
            #pragma unroll
            for (int r = 0; r < 4; ++r) {
                const int row = quad * 4 + r;
                const int col = 16 * g + l15;
                if (w == 3)
                    sOUT[row * 64 + col] = acc[g][r];
                else if (w == 0)
                    sQQ[row * 128 + 2 * col] = (unsigned short)f2bf(acc[g][r]);
                else if (w == 4)
                    sQQ[row * 128 + 2 * col + 1] = (unsigned short)f2bf(acc[g][r]);
                else   // by-dim layout: d*4 + h + 2*isV  (d=col&31, h=col>>5)
                    sKV[row * 128 + (col & 31) * 4 + (col >> 5) + 2 * (w == 2)] =
                        (unsigned short)f2bf(acc[g][r]);
            }
        }
        __syncthreads();                        // results visible

        // ---- contiguous full-line epilogue: 3 x 4KB block copies ----
        if (tid < 256) {
            ((uint4*)(qq + (size_t)nb * 128))[tid]       = ((const uint4*)sQQ)[tid];
            ((uint4*)(zkv + (size_t)nb * 128))[tid]      = ((const uint4*)sKV)[tid];
            ((float4*)(out + (size_t)nb * OUT_DIM))[tid] = ((const float4*)sOUT)[tid];
        }
    }
}

// ---------------------------------------------------------------------------
// hist_k: standalone 8-replica dst histogram + rank capture (verified r0/r8).
// ---------------------------------------------------------------------------
__global__ __launch_bounds__(256) void hist_k(
    const int* __restrict__ dst, int* __restrict__ cntr, int* __restrict__ rank)
{
    const int e = blockIdx.x * 256 + threadIdx.x;   // 3125*256 == E
    rank[e] = atomicAdd(&cntr[((e >> 8) & 7) * N_NODES + dst[e]], 1);
}

// ---------------------------------------------------------------------------
// scan1 / scan2: exclusive scans of the 8-replica histogram (verified r0/r8).
// ---------------------------------------------------------------------------
__global__ __launch_bounds__(256) void scan1_k(int* __restrict__ cntr,
                                               int* __restrict__ base,
                                               int* __restrict__ bsum,
                                               int* __restrict__ deg)
{
    __shared__ int sh[256];
    const int i = blockIdx.x * 256 + threadIdx.x;
    int tot = 0;
    if (i < N_NODES) {
        int off = 0;
        #pragma unroll
        for (int r = 0; r < 8; ++r) {
            const int c = cntr[r * N_NODES + i];
            cntr[r * N_NODES + i] = off;
            off += c;
        }
        tot = off;
        deg[i] = tot;
    }
    sh[threadIdx.x] = tot;
    __syncthreads();
    int val = tot;
    for (int off = 1; off < 256; off <<= 1) {
        const int y = (threadIdx.x >= off) ? sh[threadIdx.x - off] : 0;
        __syncthreads();
        val += y; sh[threadIdx.x] = val;
        __syncthreads();
    }
    if (i < N_NODES) base[i] = val - tot;
    if (threadIdx.x == 255) bsum[blockIdx.x] = val;
}

__global__ __launch_bounds__(256) void scan2_k(int* __restrict__ bsum)
{
    __shared__ int sh[256];
    const int i = threadIdx.x;
    const int v = (i < NB_SCAN) ? bsum[i] : 0;
    sh[i] = v;
    __syncthreads();
    int val = v;
    for (int off = 1; off < 256; off <<= 1) {
        const int y = (i >= off) ? sh[i - off] : 0;
        __syncthreads();
        val += y; sh[i] = val;
        __syncthreads();
    }
    if (i < NB_SCAN) bsum[i] = val - v;
}

// ---------------------------------------------------------------------------
// scatter_k: ATOMIC-FREE 8B scatter (verified r0/r8 position math).
// ---------------------------------------------------------------------------
__global__ __launch_bounds__(256) void scatter_k(
    const int* __restrict__ srcA, const int* __restrict__ dstA,
    const float* __restrict__ tA, const int* __restrict__ rank,
    const int* __restrict__ base, const int* __restrict__ bsum,
    const int* __restrict__ cntr, float2* __restrict__ edata2)
{
    const int e = blockIdx.x * 256 + threadIdx.x;   // 3125*256 == E
    const int d = dstA[e];
    const int pos = base[d] + bsum[d >> 8]
                  + cntr[((e >> 8) & 7) * N_NODES + d] + rank[e];
    float2 rc;
    rc.x = __int_as_float(srcA[e]);
    rc.y = tA[e];
    edata2[pos] = rc;
}

// ---------------------------------------------------------------------------
// agg_k v4: same pair structure as r9 (verified), plus: (a) 6-pair batches
// (12 records of gathers in flight), (b) 1/2pi folded into per-lane w/b so
// te = v_fract+v_cos (no per-pair radians->rev mul), (c) node0 param — the
// kernel is launched TWICE (2x 6250 blocks) so each dispatch drops to ~25us,
// letting the hidden kernels surface in the next profile's top-5.
// ---------------------------------------------------------------------------
__global__ __launch_bounds__(256) void agg_k(
    const float2* __restrict__ edata2, const int* __restrict__ base,
    const int* __restrict__ bsum, const int* __restrict__ degA,
    const float* __restrict__ w_time, const float* __restrict__ b_time,
    const unsigned short* __restrict__ qq,
    const unsigned short* __restrict__ zkv,
    const float* __restrict__ We_v, float* __restrict__ out, int node0)
{
    __shared__ float recs[4][64];               // epilogue strips only
    const int tid  = threadIdx.x;
    const int w    = tid >> 6;
    const int lane = tid & 63;
    const int h    = lane >> 5;                 // which record of the pair
    const int l31  = lane & 31;                 // dim
    const int n    = node0 + blockIdx.x * 4 + w;

    const int b0  = base[n] + bsum[n >> 8];
    const int deg = degA[n];

    const float wt = w_time[l31] * INV2PI;      // revolutions domain
    const float bt = b_time[l31] * INV2PI;

    // dst-side q/qek for BOTH heads at this dim, once; fold log2e.
    const unsigned qv0 = *(const unsigned*)(qq + (size_t)n * 128 + 2 * l31);
    const unsigned qv1 = *(const unsigned*)(qq + (size_t)n * 128 + 64 + 2 * l31);
    const float q0  = lo16(qv0) * LOG2E, qe0 = hi16(qv0) * LOG2E;
    const float q1  = lo16(qv1) * LOG2E, qe1 = hi16(qv1) * LOG2E;

    float av0 = 0.f, av1 = 0.f, pte0 = 0.f, pte1 = 0.f, lp0 = 0.f, lp1 = 0.f;

    #define PAIR_COMPUTE(RR, KV, MASKED)                                     \
    {                                                                        \
        const float te = cos_rev(fmaf((RR).y, wt, bt));                      \
        float p0 = q0 * lo16((KV).x) + qe0 * te;                             \
        float p1 = q1 * hi16((KV).x) + qe1 * te;                             \
        p0 = half_reduce(p0);                                                \
        p1 = half_reduce(p1);                                                \
        float pe0 = exp2f(p0), pe1 = exp2f(p1);                              \
        if (MASKED) { if (h) { pe0 = 0.f; pe1 = 0.f; } }                     \
        av0  += pe0 * lo16((KV).y);                                          \
        av1  += pe1 * hi16((KV).y);                                          \
        pte0 += pe0 * te;                                                    \
        pte1 += pe1 * te;                                                    \
        lp0  += pe0;                                                         \
        lp1  += pe1;                                                         \
    }

    const int fp = deg >> 1;                    // full pairs
    int p = 0;
    for (; p + 6 <= fp; p += 6) {               // 6 pairs = 12 records batched
        float2 r[6];
        #pragma unroll
        for (int j = 0; j < 6; ++j) r[j] = edata2[b0 + 2 * (p + j) + h];
        uint2 kv[6];
        #pragma unroll
        for (int j = 0; j < 6; ++j)
            kv[j] = *(const uint2*)((const char*)zkv +
                      (((unsigned)__float_as_int(r[j].x)) << 8) + (l31 << 3));
        #pragma unroll
        for (int j = 0; j < 6; ++j) PAIR_COMPUTE(r[j], kv[j], false)
    }
    for (; p < fp; ++p) {                       // leftover full pairs
        const float2 r = edata2[b0 + 2 * p + h];
        const uint2 kv = *(const uint2*)((const char*)zkv +
                      (((unsigned)__float_as_int(r.x)) << 8) + (l31 << 3));
        PAIR_COMPUTE(r, kv, false)
    }
    if (deg & 1) {                              // odd last record: lower half only
        const float2 r = edata2[b0 + deg - 1];
        const uint2 kv = *(const uint2*)((const char*)zkv +
                      (((unsigned)__float_as_int(r.x)) << 8) + (l31 << 3));
        PAIR_COMPUTE(r, kv, true)
    }
    #undef PAIR_COMPUTE

    // ---- merge halves (even-record sums + odd-record sums) ----
    av0  += __shfl_xor(av0, 32);
    av1  += __shfl_xor(av1, 32);
    pte0 += __shfl_xor(pte0, 32);
    pte1 += __shfl_xor(pte1, 32);
    lp0  += __shfl_xor(lp0, 32);
    lp1  += __shfl_xor(lp1, 32);

    // ---- fused We_v epilogue (rec[h*32+d] = pte[h][d]) ----
    float* rec = &recs[w][0];
    rec[lane] = h ? pte1 : pte0;
    float wev[32];
    #pragma unroll
    for (int k = 0; k < 32; ++k) wev[k] = We_v[k * 64 + lane];

    const float lp  = h ? lp1 : lp0;
    const float av  = h ? av1 : av0;
    const float inv = (lp > 0.f) ? 1.f / lp : 0.f;
    const float4* pv = (const float4*)(rec + h * 32);
    float dot = 0.f;
    #pragma unroll
    for (int k = 0; k < 8; ++k) {
        const float4 c = pv[k];
        dot += c.x * wev[4 * k]     + c.y * wev[4 * k + 1]
             + c.z * wev[4 * k + 2] + c.w * wev[4 * k + 3];
    }

    out[(size_t)n * OUT_DIM + lane] += (av + dot) * inv;   // skip already there
}

extern "C" void kernel_launch(void* const* d_in, const int* in_sizes, int n_in,
                              void* d_out, int out_size, void* d_ws, size_t ws_size,
                              hipStream_t stream) {
    (void)in_sizes; (void)n_in; (void)out_size; (void)ws_size;
    const int*   src    = (const int*)d_in[0];
    const int*   dst    = (const int*)d_in[1];
    const float* t      = (const float*)d_in[2];
    const float* x      = (const float*)d_in[3];
    const float* mem    = (const float*)d_in[4];
    const float* w_time = (const float*)d_in[5];
    const float* b_time = (const float*)d_in[6];
    const float* Wq     = (const float*)d_in[7];
    const float* Wk     = (const float*)d_in[8];
    const float* Wv     = (const float*)d_in[9];
    const float* We_k   = (const float*)d_in[10];
    const float* We_v   = (const float*)d_in[11];
    const float* Wskip  = (const float*)d_in[12];

    // workspace layout (16B-aligned chunks)
    char* p = (char*)d_ws;
    unsigned short* zkv = (unsigned short*)p; p += (size_t)N_NODES * 128 * 2; // 12.8 MB (by-dim k/v)
    unsigned short* qq  = (unsigned short*)p; p += (size_t)N_NODES * 128 * 2; // 12.8 MB (q|qek interleaved)
    unsigned short* wtb = (unsigned short*)p; p += (size_t)5 * 64 * 160 * 2;  // 100 KB
    float2* edata2 = (float2*)p; p += (size_t)N_EDGES * 8;                    // 6.4 MB
    int*  cntr  = (int*)p;   p += (size_t)8 * N_NODES * 4;   // zeroed in prep_k
    int*  rank  = (int*)p;   p += (size_t)N_EDGES * 4;       // 3.2 MB
    int*  base  = (int*)p;   p += (size_t)N_NODES * 4;
    int*  deg   = (int*)p;   p += (size_t)N_NODES * 4;
    int*  bsum  = (int*)p;   p += 256 * 4;
    float* out  = (float*)d_out;

    prep_k   <<<1600, 256, 0, stream>>>(Wq, Wk, Wv, Wskip, We_k, wtb, cntr);
    node_gemm<<<NGB, 320, 0, stream>>>(x, mem, wtb, qq, zkv, out);
    hist_k   <<<N_EDGES / 256, 256, 0, stream>>>(dst, cntr, rank);
    scan1_k  <<<NB_SCAN, 256, 0, stream>>>(cntr, base, bsum, deg);
    scan2_k  <<<1, 256, 0, stream>>>(bsum);
    scatter_k<<<N_EDGES / 256, 256, 0, stream>>>(src, dst, t, rank, base, bsum,
                                                 cntr, edata2);
    agg_k    <<<N_NODES / 8, 256, 0, stream>>>(edata2, base, bsum, deg,
                                               w_time, b_time, qq, zkv, We_v,
                                               out, 0);
    agg_k    <<<N_NODES / 8, 256, 0, stream>>>(edata2, base, bsum, deg,
                                               w_time, b_time, qq, zkv, We_v,
                                               out, N_NODES / 2);
}

// Round 11
// 240.048 us; speedup vs baseline: 1.0477x; 1.0477x over previous
//
#include <hip/hip_runtime.h>
#include <hip/hip_bf16.h>
#include <math.h>

#define N_NODES 50000
#define N_EDGES 800000
#define IN_DIM  128
#define MEM_DIM 32
#define OUT_DIM 64
#define NB_SCAN ((N_NODES + 255) / 256)   // 196
#define SCALE   0.17677669529663687f      // 1/sqrt(32)
#define LOG2E   1.44269504088896f
#define LDS_AROW 168                      // padded A-tile row stride (elems)
#define NGB 625                           // GEMM blocks (5 tiles of 16 nodes each)

typedef __attribute__((ext_vector_type(8))) short bf16x8;
typedef __attribute__((ext_vector_type(4))) float f32x4;

__device__ __forceinline__ short f2bf(float f) {
    union { float f; unsigned u; } v; v.f = f;
    unsigned r = v.u + 0x7FFF + ((v.u >> 16) & 1);   // round-to-nearest-even
    return (short)(r >> 16);
}
__device__ __forceinline__ float lo16(unsigned u) { return __uint_as_float(u << 16); }
__device__ __forceinline__ float hi16(unsigned u) { return __uint_as_float(u & 0xffff0000u); }

// Cross-lane add via DPP (VALU pipe, not LDS). CTRL: 0xB1=quad_perm xor1,
// 0x4E=quad_perm xor2, 0x124=row_ror:4, 0x128=row_ror:8.
template <int CTRL>
__device__ __forceinline__ float dpp_mov(float x) {
    return __int_as_float(__builtin_amdgcn_update_dpp(
        0, __float_as_int(x), CTRL, 0xF, 0xF, true));
}
// xor16 within each 32-lane half (BitMode: xor=16, and=0x1F)
__device__ __forceinline__ float swz16(float x) {
    return __int_as_float(__builtin_amdgcn_ds_swizzle(__float_as_int(x), 0x401F));
}
// sum over the lane's 32-lane half: 4 DPP adds + 1 swizzle. Each 32-lane
// half reduces INDEPENDENTLY (one pass serves 2 records).
__device__ __forceinline__ float half_reduce(float pr) {
    pr += dpp_mov<0xB1>(pr);
    pr += dpp_mov<0x4E>(pr);
    pr += dpp_mov<0x124>(pr);
    pr += dpp_mov<0x128>(pr);
    pr += swz16(pr);
    return pr;
}

// ---------------------------------------------------------------------------
// prep_k: bf16 weight bank in LANE-COALESCED B-frag layout (verified r5/r8).
// Also zeroes the 8-replica histogram.
// ---------------------------------------------------------------------------
__global__ __launch_bounds__(256) void prep_k(
    const float* __restrict__ Wq, const float* __restrict__ Wk,
    const float* __restrict__ Wv, const float* __restrict__ Wskip,
    const float* __restrict__ We_k, unsigned short* __restrict__ wtb,
    int* __restrict__ cntr)
{
    const int i = blockIdx.x * 256 + threadIdx.x;   // 1600*256 = 409600
    if (i < 8 * N_NODES) cntr[i] = 0;
    if (i >= 51200) return;                         // 5*64*160
    const int m = i / 10240, rem = i % 10240, c = rem / 160, k = rem % 160;
    float v;
    if (m == 4) {
        const int h = c >> 5, kk = c & 31;
        v = 0.f;
        #pragma unroll
        for (int j = 0; j < 32; ++j)
            v += Wq[k * 64 + h * 32 + j] * We_k[kk * 64 + h * 32 + j];
        v *= SCALE;
    } else {
        const float* W = (m == 0) ? Wq : (m == 1) ? Wk : (m == 2) ? Wv : Wskip;
        v = W[k * 64 + c];
        if (m == 0) v *= SCALE;
    }
    const int g = c >> 4, l15 = c & 15;
    const int kb = k >> 5, quad = (k >> 3) & 3, j = k & 7;
    wtb[(size_t)((((m * 5 + kb) * 4 + g) * 64) + quad * 16 + l15) * 8 + j] =
        (unsigned short)f2bf(v);
}

// ---------------------------------------------------------------------------
// hist_k: standalone 8-replica dst histogram + rank capture (verified r0/r8).
// ---------------------------------------------------------------------------
__global__ __launch_bounds__(256) void hist_k(
    const int* __restrict__ dst, int* __restrict__ cntr, int* __restrict__ rank)
{
    const int e = blockIdx.x * 256 + threadIdx.x;   // 3125*256 == E
    rank[e] = atomicAdd(&cntr[((e >> 8) & 7) * N_NODES + dst[e]], 1);
}

// ---------------------------------------------------------------------------
// scan1 / scan2: exclusive scans of the 8-replica histogram (verified r0/r8).
// ---------------------------------------------------------------------------
__global__ __launch_bounds__(256) void scan1_k(int* __restrict__ cntr,
                                               int* __restrict__ base,
                                               int* __restrict__ bsum,
                                               int* __restrict__ deg)
{
    __shared__ int sh[256];
    const int i = blockIdx.x * 256 + threadIdx.x;
    int tot = 0;
    if (i < N_NODES) {
        int off = 0;
        #pragma unroll
        for (int r = 0; r < 8; ++r) {
            const int c = cntr[r * N_NODES + i];
            cntr[r * N_NODES + i] = off;
            off += c;
        }
        tot = off;
        deg[i] = tot;
    }
    sh[threadIdx.x] = tot;
    __syncthreads();
    int val = tot;
    for (int off = 1; off < 256; off <<= 1) {
        const int y = (threadIdx.x >= off) ? sh[threadIdx.x - off] : 0;
        __syncthreads();
        val += y; sh[threadIdx.x] = val;
        __syncthreads();
    }
    if (i < N_NODES) base[i] = val - tot;
    if (threadIdx.x == 255) bsum[blockIdx.x] = val;
}

__global__ __launch_bounds__(256) void scan2_k(int* __restrict__ bsum)
{
    __shared__ int sh[256];
    const int i = threadIdx.x;
    const int v = (i < NB_SCAN) ? bsum[i] : 0;
    sh[i] = v;
    __syncthreads();
    int val = v;
    for (int off = 1; off < 256; off <<= 1) {
        const int y = (i >= off) ? sh[i - off] : 0;
        __syncthreads();
        val += y; sh[i] = val;
        __syncthreads();
    }
    if (i < NB_SCAN) bsum[i] = val - v;
}

// ---------------------------------------------------------------------------
// gemm_scatter_k: the two INDEPENDENT post-scan arms fused into one dispatch
// so they overlap (MFMA-heavy GEMM || memory-latency-heavy scatter; no
// stream forking available under graph capture). Blocks [0,NGB): the r8/r9-
// verified 5-tile node GEMM body (zkv BY-DIM layout). Blocks [NGB,3125):
// the r8-verified atomic-free scatter, re-indexed to 320-thread blocks
// (position math is a pure function of the absolute edge id e).
// ---------------------------------------------------------------------------
__global__ __launch_bounds__(320) void gemm_scatter_k(
    const float* __restrict__ x, const float* __restrict__ mem,
    const unsigned short* __restrict__ wtb,
    unsigned short* __restrict__ qq, unsigned short* __restrict__ zkv,
    float* __restrict__ out,
    const int* __restrict__ srcA, const int* __restrict__ dstA,
    const float* __restrict__ tA, const int* __restrict__ rank,
    const int* __restrict__ base, const int* __restrict__ bsum,
    const int* __restrict__ cntr, float2* __restrict__ edata2)
{
    const int tid = threadIdx.x;
    if (blockIdx.x >= NGB) {
        const int e = (blockIdx.x - NGB) * 320 + tid;   // 2500*320 == E
        const int d = dstA[e];
        const int pos = base[d] + bsum[d >> 8]
                      + cntr[((e >> 8) & 7) * N_NODES + d] + rank[e];
        float2 rc;
        rc.x = __int_as_float(srcA[e]);
        rc.y = tA[e];
        edata2[pos] = rc;
        return;
    }
    __shared__ unsigned short sA[16 * LDS_AROW];    // 5.25 KB bf16 in-tile
    __shared__ unsigned short sQQ[16 * 128];        // 4 KB
    __shared__ unsigned short sKV[16 * 128];        // 4 KB
    __shared__ float          sOUT[16 * 64];        // 4 KB

    const int w    = tid >> 6;                  // 0..4 (matrix id)
    const int lane = tid & 63;
    const int l15  = lane & 15;
    const int quad = lane >> 4;

    // ---- B-frags: once per block, fully coalesced (1KB per instruction) ----
    bf16x8 bfrag[5][4];
    #pragma unroll
    for (int kb = 0; kb < 5; ++kb)
        #pragma unroll
        for (int g = 0; g < 4; ++g)
            bfrag[kb][g] = *(const bf16x8*)(wtb +
                (size_t)(((w * 5 + kb) * 4 + g) * 64 + lane) * 8);

    // ---- fixed per-thread A-stage assignment (2 float4 each, 640 total) ----
    int nb = blockIdx.x * 80;
    const int r0 = tid >> 5, d0 = (tid & 31) * 4;
    const bool u1x = (tid < 192);
    const int i1 = tid + 320;
    const int r1 = u1x ? (i1 >> 5) : ((tid - 192) >> 3);
    const int d1 = u1x ? ((i1 & 31) * 4) : (((tid - 192) & 7) * 4);
    const float* p0 = x + (size_t)(nb + r0) * IN_DIM + d0;
    const float* p1 = u1x ? (x + (size_t)(nb + r1) * IN_DIM + d1)
                          : (mem + (size_t)(nb + r1) * MEM_DIM + d1);
    const int adv1 = u1x ? 16 * IN_DIM : 16 * MEM_DIM;
    unsigned short* s0 = sA + r0 * LDS_AROW + d0;
    unsigned short* s1 = sA + r1 * LDS_AROW + (u1x ? d1 : 128 + d1);

    // prologue: load tile 0
    float4 c0 = *(const float4*)p0; p0 += 16 * IN_DIM;
    float4 c1 = *(const float4*)p1; p1 += adv1;

    for (int t = 0; t < 5; ++t, nb += 16) {
        __syncthreads();                        // sA reusable
        s0[0] = (unsigned short)f2bf(c0.x); s0[1] = (unsigned short)f2bf(c0.y);
        s0[2] = (unsigned short)f2bf(c0.z); s0[3] = (unsigned short)f2bf(c0.w);
        s1[0] = (unsigned short)f2bf(c1.x); s1[1] = (unsigned short)f2bf(c1.y);
        s1[2] = (unsigned short)f2bf(c1.z); s1[3] = (unsigned short)f2bf(c1.w);
        __syncthreads();                        // A-tile visible

        if (t < 4) {                            // prefetch next tile
            c0 = *(const float4*)p0; p0 += 16 * IN_DIM;
            c1 = *(const float4*)p1; p1 += adv1;
        }

        f32x4 acc[4];
        #pragma unroll
        for (int g = 0; g < 4; ++g) acc[g] = (f32x4)0.0f;
        #pragma unroll
        for (int kb = 0; kb < 5; ++kb) {
            const bf16x8 afrag =
                *(const bf16x8*)(sA + l15 * LDS_AROW + kb * 32 + quad * 8);
            #pragma unroll
            for (int g = 0; g < 4; ++g)
                acc[g] = __builtin_amdgcn_mfma_f32_16x16x32_bf16(
                             afrag, bfrag[kb][g], acc[g], 0, 0, 0);
        }

        // ---- stage results into LDS out-tiles ----
        #pragma unroll
        for (int g = 0; g < 4; ++g) {
            #pragma unroll
            for (int r = 0; r < 4; ++r) {
                const int row = quad * 4 + r;
                const int col = 16 * g + l15;
                if (w == 3)
                    sOUT[row * 64 + col] = acc[g][r];
                else if (w == 0)
                    sQQ[row * 128 + 2 * col] = (unsigned short)f2bf(acc[g][r]);
                else if (w == 4)
                    sQQ[row * 128 + 2 * col + 1] = (unsigned short)f2bf(acc[g][r]);
                else   // by-dim layout: d*4 + h + 2*isV  (d=col&31, h=col>>5)
                    sKV[row * 128 + (col & 31) * 4 + (col >> 5) + 2 * (w == 2)] =
                        (unsigned short)f2bf(acc[g][r]);
            }
        }
        __syncthreads();                        // results visible

        // ---- contiguous full-line epilogue: 3 x 4KB block copies ----
        if (tid < 256) {
            ((uint4*)(qq + (size_t)nb * 128))[tid]       = ((const uint4*)sQQ)[tid];
            ((uint4*)(zkv + (size_t)nb * 128))[tid]      = ((const uint4*)sKV)[tid];
            ((float4*)(out + (size_t)nb * OUT_DIM))[tid] = ((const float4*)sOUT)[tid];
        }
    }
}

// ---------------------------------------------------------------------------
// agg_k: r9-verified body VERBATIM (single dispatch; the r10 split/trims
// regressed). One wave per node, two records per iteration via the by-dim
// zkv layout; DPP half_reduce serves both records in one pass per head.
// ---------------------------------------------------------------------------
__global__ __launch_bounds__(256) void agg_k(
    const float2* __restrict__ edata2, const int* __restrict__ base,
    const int* __restrict__ bsum, const int* __restrict__ degA,
    const float* __restrict__ w_time, const float* __restrict__ b_time,
    const unsigned short* __restrict__ qq,
    const unsigned short* __restrict__ zkv,
    const float* __restrict__ We_v, float* __restrict__ out)
{
    __shared__ float recs[4][64];               // epilogue strips only
    const int tid  = threadIdx.x;
    const int w    = tid >> 6;
    const int lane = tid & 63;
    const int h    = lane >> 5;                 // which record of the pair
    const int l31  = lane & 31;                 // dim
    const int n    = blockIdx.x * 4 + w;

    const int b0  = base[n] + bsum[n >> 8];
    const int deg = degA[n];

    const float wt = w_time[l31];
    const float bt = b_time[l31];

    // dst-side q/qek for BOTH heads at this dim, once; fold log2e.
    const unsigned qv0 = *(const unsigned*)(qq + (size_t)n * 128 + 2 * l31);
    const unsigned qv1 = *(const unsigned*)(qq + (size_t)n * 128 + 64 + 2 * l31);
    const float q0  = lo16(qv0) * LOG2E, qe0 = hi16(qv0) * LOG2E;
    const float q1  = lo16(qv1) * LOG2E, qe1 = hi16(qv1) * LOG2E;

    float av0 = 0.f, av1 = 0.f, pte0 = 0.f, pte1 = 0.f, lp0 = 0.f, lp1 = 0.f;

    #define PAIR_COMPUTE(RR, KV, MASKED)                                     \
    {                                                                        \
        const float te = __cosf((RR).y * wt + bt);                           \
        float p0 = q0 * lo16((KV).x) + qe0 * te;                             \
        float p1 = q1 * hi16((KV).x) + qe1 * te;                             \
        p0 = half_reduce(p0);                                                \
        p1 = half_reduce(p1);                                                \
        float pe0 = exp2f(p0), pe1 = exp2f(p1);                              \
        if (MASKED) { if (h) { pe0 = 0.f; pe1 = 0.f; } }                     \
        av0  += pe0 * lo16((KV).y);                                          \
        av1  += pe1 * hi16((KV).y);                                          \
        pte0 += pe0 * te;                                                    \
        pte1 += pe1 * te;                                                    \
        lp0  += pe0;                                                         \
        lp1  += pe1;                                                         \
    }

    const int fp = deg >> 1;                    // full pairs
    int p = 0;
    for (; p + 4 <= fp; p += 4) {               // 4 pairs = 8 records batched
        float2 r[4];
        #pragma unroll
        for (int j = 0; j < 4; ++j) r[j] = edata2[b0 + 2 * (p + j) + h];
        uint2 kv[4];
        #pragma unroll
        for (int j = 0; j < 4; ++j)
            kv[j] = *(const uint2*)((const char*)zkv +
                      (((unsigned)__float_as_int(r[j].x)) << 8) + (l31 << 3));
        #pragma unroll
        for (int j = 0; j < 4; ++j) PAIR_COMPUTE(r[j], kv[j], false)
    }
    for (; p < fp; ++p) {                       // leftover full pairs
        const float2 r = edata2[b0 + 2 * p + h];
        const uint2 kv = *(const uint2*)((const char*)zkv +
                      (((unsigned)__float_as_int(r.x)) << 8) + (l31 << 3));
        PAIR_COMPUTE(r, kv, false)
    }
    if (deg & 1) {                              // odd last record: lower half only
        const float2 r = edata2[b0 + deg - 1];
        const uint2 kv = *(const uint2*)((const char*)zkv +
                      (((unsigned)__float_as_int(r.x)) << 8) + (l31 << 3));
        PAIR_COMPUTE(r, kv, true)
    }
    #undef PAIR_COMPUTE

    // ---- merge halves (even-record sums + odd-record sums) ----
    av0  += __shfl_xor(av0, 32);
    av1  += __shfl_xor(av1, 32);
    pte0 += __shfl_xor(pte0, 32);
    pte1 += __shfl_xor(pte1, 32);
    lp0  += __shfl_xor(lp0, 32);
    lp1  += __shfl_xor(lp1, 32);

    // ---- fused We_v epilogue (rec[h*32+d] = pte[h][d]) ----
    float* rec = &recs[w][0];
    rec[lane] = h ? pte1 : pte0;
    float wev[32];
    #pragma unroll
    for (int k = 0; k < 32; ++k) wev[k] = We_v[k * 64 + lane];

    const float lp  = h ? lp1 : lp0;
    const float av  = h ? av1 : av0;
    const float inv = (lp > 0.f) ? 1.f / lp : 0.f;
    const float4* pv = (const float4*)(rec + h * 32);
    float dot = 0.f;
    #pragma unroll
    for (int k = 0; k < 8; ++k) {
        const float4 c = pv[k];
        dot += c.x * wev[4 * k]     + c.y * wev[4 * k + 1]
             + c.z * wev[4 * k + 2] + c.w * wev[4 * k + 3];
    }

    out[(size_t)n * OUT_DIM + lane] += (av + dot) * inv;   // skip already there
}

extern "C" void kernel_launch(void* const* d_in, const int* in_sizes, int n_in,
                              void* d_out, int out_size, void* d_ws, size_t ws_size,
                              hipStream_t stream) {
    (void)in_sizes; (void)n_in; (void)out_size; (void)ws_size;
    const int*   src    = (const int*)d_in[0];
    const int*   dst    = (const int*)d_in[1];
    const float* t      = (const float*)d_in[2];
    const float* x      = (const float*)d_in[3];
    const float* mem    = (const float*)d_in[4];
    const float* w_time = (const float*)d_in[5];
    const float* b_time = (const float*)d_in[6];
    const float* Wq     = (const float*)d_in[7];
    const float* Wk     = (const float*)d_in[8];
    const float* Wv     = (const float*)d_in[9];
    const float* We_k   = (const float*)d_in[10];
    const float* We_v   = (const float*)d_in[11];
    const float* Wskip  = (const float*)d_in[12];

    // workspace layout (16B-aligned chunks)
    char* p = (char*)d_ws;
    unsigned short* zkv = (unsigned short*)p; p += (size_t)N_NODES * 128 * 2; // 12.8 MB (by-dim k/v)
    unsigned short* qq  = (unsigned short*)p; p += (size_t)N_NODES * 128 * 2; // 12.8 MB (q|qek interleaved)
    unsigned short* wtb = (unsigned short*)p; p += (size_t)5 * 64 * 160 * 2;  // 100 KB
    float2* edata2 = (float2*)p; p += (size_t)N_EDGES * 8;                    // 6.4 MB
    int*  cntr  = (int*)p;   p += (size_t)8 * N_NODES * 4;   // zeroed in prep_k
    int*  rank  = (int*)p;   p += (size_t)N_EDGES * 4;       // 3.2 MB
    int*  base  = (int*)p;   p += (size_t)N_NODES * 4;
    int*  deg   = (int*)p;   p += (size_t)N_NODES * 4;
    int*  bsum  = (int*)p;   p += 256 * 4;
    float* out  = (float*)d_out;

    prep_k   <<<1600, 256, 0, stream>>>(Wq, Wk, Wv, Wskip, We_k, wtb, cntr);
    hist_k   <<<N_EDGES / 256, 256, 0, stream>>>(dst, cntr, rank);
    scan1_k  <<<NB_SCAN, 256, 0, stream>>>(cntr, base, bsum, deg);
    scan2_k  <<<1, 256, 0, stream>>>(bsum);
    gemm_scatter_k<<<NGB + 2500, 320, 0, stream>>>(x, mem, wtb, qq, zkv, out,
                                                   src, dst, t, rank, base,
                                                   bsum, cntr, edata2);
    agg_k    <<<N_NODES / 4, 256, 0, stream>>>(edata2, base, bsum, deg,
                                               w_time, b_time, qq, zkv, We_v, out);
}

// Round 12
// 239.207 us; speedup vs baseline: 1.0514x; 1.0035x over previous
//
#include <hip/hip_runtime.h>
#include <hip/hip_bf16.h>
#include <math.h>

#define N_NODES 50000
#define N_EDGES 800000
#define IN_DIM  128
#define MEM_DIM 32
#define OUT_DIM 64
#define NB_SCAN ((N_NODES + 255) / 256)   // 196
#define SCALE   0.17677669529663687f      // 1/sqrt(32)
#define LOG2E   1.44269504088896f
#define LDS_AROW 168                      // padded A-tile row stride (elems)
#define NGB 3125                          // single-tile GEMM blocks (16 nodes each)
#define NPREP 200                         // prep blocks (200*256 == 51200)

typedef __attribute__((ext_vector_type(8))) short bf16x8;
typedef __attribute__((ext_vector_type(4))) float f32x4;

__device__ __forceinline__ short f2bf(float f) {
    union { float f; unsigned u; } v; v.f = f;
    unsigned r = v.u + 0x7FFF + ((v.u >> 16) & 1);   // round-to-nearest-even
    return (short)(r >> 16);
}
__device__ __forceinline__ float lo16(unsigned u) { return __uint_as_float(u << 16); }
__device__ __forceinline__ float hi16(unsigned u) { return __uint_as_float(u & 0xffff0000u); }

// Cross-lane add via DPP (VALU pipe, not LDS). CTRL: 0xB1=quad_perm xor1,
// 0x4E=quad_perm xor2, 0x124=row_ror:4, 0x128=row_ror:8.
template <int CTRL>
__device__ __forceinline__ float dpp_mov(float x) {
    return __int_as_float(__builtin_amdgcn_update_dpp(
        0, __float_as_int(x), CTRL, 0xF, 0xF, true));
}
// xor16 within each 32-lane half (BitMode: xor=16, and=0x1F)
__device__ __forceinline__ float swz16(float x) {
    return __int_as_float(__builtin_amdgcn_ds_swizzle(__float_as_int(x), 0x401F));
}
// sum over the lane's 32-lane half: 4 DPP adds + 1 swizzle. Each 32-lane
// half reduces INDEPENDENTLY (one pass serves 2 records).
__device__ __forceinline__ float half_reduce(float pr) {
    pr += dpp_mov<0xB1>(pr);
    pr += dpp_mov<0x4E>(pr);
    pr += dpp_mov<0x124>(pr);
    pr += dpp_mov<0x128>(pr);
    pr += swz16(pr);
    return pr;
}

// ---------------------------------------------------------------------------
// prep_hist_k: prep (blocks [0,NPREP)) and hist (blocks [NPREP,NPREP+3125))
// fused — independent work given cntr pre-zeroed by hipMemsetAsync. prep:
// bf16 weight bank in lane-coalesced B-frag layout (verified r5/r8). hist:
// 8-replica dst histogram + rank capture (verified r0/r8; pure function of
// absolute edge id e).
// ---------------------------------------------------------------------------
__global__ __launch_bounds__(256) void prep_hist_k(
    const float* __restrict__ Wq, const float* __restrict__ Wk,
    const float* __restrict__ Wv, const float* __restrict__ Wskip,
    const float* __restrict__ We_k, unsigned short* __restrict__ wtb,
    const int* __restrict__ dst, int* __restrict__ cntr, int* __restrict__ rank)
{
    if (blockIdx.x >= NPREP) {
        const int e = (blockIdx.x - NPREP) * 256 + threadIdx.x;   // 3125*256 == E
        rank[e] = atomicAdd(&cntr[((e >> 8) & 7) * N_NODES + dst[e]], 1);
        return;
    }
    const int i = blockIdx.x * 256 + threadIdx.x;   // < 51200 == 5*64*160
    const int m = i / 10240, rem = i % 10240, c = rem / 160, k = rem % 160;
    float v;
    if (m == 4) {
        const int h = c >> 5, kk = c & 31;
        v = 0.f;
        #pragma unroll
        for (int j = 0; j < 32; ++j)
            v += Wq[k * 64 + h * 32 + j] * We_k[kk * 64 + h * 32 + j];
        v *= SCALE;
    } else {
        const float* W = (m == 0) ? Wq : (m == 1) ? Wk : (m == 2) ? Wv : Wskip;
        v = W[k * 64 + c];
        if (m == 0) v *= SCALE;
    }
    const int g = c >> 4, l15 = c & 15;
    const int kb = k >> 5, quad = (k >> 3) & 3, j = k & 7;
    wtb[(size_t)((((m * 5 + kb) * 4 + g) * 64) + quad * 16 + l15) * 8 + j] =
        (unsigned short)f2bf(v);
}

// ---------------------------------------------------------------------------
// scan12_k: scan1 (verified r0/r8) + scan2 folded in via the last-block
// pattern: each block fences its bsum write, bumps a device counter; the
// 196th block re-reads all bsum entries (volatile, after an acquire fence)
// and performs the 196-element exclusive scan in place. Saves a dispatch.
// ---------------------------------------------------------------------------
__global__ __launch_bounds__(256) void scan12_k(int* __restrict__ cntr,
                                                int* __restrict__ base,
                                                int* __restrict__ bsum,
                                                int* __restrict__ deg,
                                                int* __restrict__ flag)
{
    __shared__ int sh[256];
    __shared__ int isLast;
    const int i = blockIdx.x * 256 + threadIdx.x;
    int tot = 0;
    if (i < N_NODES) {
        int off = 0;
        #pragma unroll
        for (int r = 0; r < 8; ++r) {
            const int c = cntr[r * N_NODES + i];
            cntr[r * N_NODES + i] = off;
            off += c;
        }
        tot = off;
        deg[i] = tot;
    }
    sh[threadIdx.x] = tot;
    __syncthreads();
    int val = tot;
    for (int off = 1; off < 256; off <<= 1) {
        const int y = (threadIdx.x >= off) ? sh[threadIdx.x - off] : 0;
        __syncthreads();
        val += y; sh[threadIdx.x] = val;
        __syncthreads();
    }
    if (i < N_NODES) base[i] = val - tot;
    if (threadIdx.x == 255) {
        bsum[blockIdx.x] = val;
        __threadfence();                         // publish bsum write
        isLast = (atomicAdd(flag, 1) == NB_SCAN - 1);
    }
    __syncthreads();
    if (!isLast) return;

    // last-arriving block: all other blocks' bsum writes are fenced+counted
    __threadfence();                             // acquire
    const int ti = threadIdx.x;
    volatile int* vb = bsum;
    const int v = (ti < NB_SCAN) ? vb[ti] : 0;
    sh[ti] = v;
    __syncthreads();
    int val2 = v;
    for (int off = 1; off < 256; off <<= 1) {
        const int y = (ti >= off) ? sh[ti - off] : 0;
        __syncthreads();
        val2 += y; sh[ti] = val2;
        __syncthreads();
    }
    if (ti < NB_SCAN) bsum[ti] = val2 - v;
}

// ---------------------------------------------------------------------------
// gemm_scatter_k: blocks [0,NGB) = SINGLE-TILE node GEMM (16 nodes each —
// 5x the block parallelism of the r11 5-tile form, now affordable because
// the lane-coalesced wtb makes per-block B-frag loads cheap/L2-resident).
// Blocks [NGB, NGB+2500) = the r8-verified atomic-free scatter. Bodies are
// the verified r3 staging + r11 MFMA/stage-out/epilogue, minus the tile loop.
// ---------------------------------------------------------------------------
__global__ __launch_bounds__(320) void gemm_scatter_k(
    const float* __restrict__ x, const float* __restrict__ mem,
    const unsigned short* __restrict__ wtb,
    unsigned short* __restrict__ qq, unsigned short* __restrict__ zkv,
    float* __restrict__ out,
    const int* __restrict__ srcA, const int* __restrict__ dstA,
    const float* __restrict__ tA, const int* __restrict__ rank,
    const int* __restrict__ base, const int* __restrict__ bsum,
    const int* __restrict__ cntr, float2* __restrict__ edata2)
{
    const int tid = threadIdx.x;
    if (blockIdx.x >= NGB) {
        const int e = (blockIdx.x - NGB) * 320 + tid;   // 2500*320 == E
        const int d = dstA[e];
        const int pos = base[d] + bsum[d >> 8]
                      + cntr[((e >> 8) & 7) * N_NODES + d] + rank[e];
        float2 rc;
        rc.x = __int_as_float(srcA[e]);
        rc.y = tA[e];
        edata2[pos] = rc;
        return;
    }
    __shared__ unsigned short sA[16 * LDS_AROW];    // 5.25 KB bf16 in-tile
    __shared__ unsigned short sQQ[16 * 128];        // 4 KB
    __shared__ unsigned short sKV[16 * 128];        // 4 KB
    __shared__ float          sOUT[16 * 64];        // 4 KB

    const int w    = tid >> 6;                  // 0..4 (matrix id)
    const int lane = tid & 63;
    const int l15  = lane & 15;
    const int quad = lane >> 4;
    const int nb   = blockIdx.x * 16;

    // ---- B-frags: coalesced 1KB loads, L2-resident wtb ----
    bf16x8 bfrag[5][4];
    #pragma unroll
    for (int kb = 0; kb < 5; ++kb)
        #pragma unroll
        for (int g = 0; g < 4; ++g)
            bfrag[kb][g] = *(const bf16x8*)(wtb +
                (size_t)(((w * 5 + kb) * 4 + g) * 64 + lane) * 8);

    // ---- cooperative coalesced stage: x (16x128) + mem (16x32) -> sA ----
    for (int i = tid; i < 640; i += 320) {
        float4 f;
        int row, dim;
        if (i < 512) {                       // x part: 16 rows x 32 float4
            row = i >> 5; dim = (i & 31) * 4;
            f = *(const float4*)(x + (size_t)(nb + row) * IN_DIM + dim);
        } else {                             // mem part: 16 rows x 8 float4
            const int j = i - 512;
            row = j >> 3; dim = 128 + (j & 7) * 4;
            f = *(const float4*)(mem + (size_t)(nb + row) * MEM_DIM + (dim - 128));
        }
        unsigned short* d2 = sA + row * LDS_AROW + dim;
        d2[0] = (unsigned short)f2bf(f.x); d2[1] = (unsigned short)f2bf(f.y);
        d2[2] = (unsigned short)f2bf(f.z); d2[3] = (unsigned short)f2bf(f.w);
    }
    __syncthreads();

    f32x4 acc[4];
    #pragma unroll
    for (int g = 0; g < 4; ++g) acc[g] = (f32x4)0.0f;
    #pragma unroll
    for (int kb = 0; kb < 5; ++kb) {
        const bf16x8 afrag =
            *(const bf16x8*)(sA + l15 * LDS_AROW + kb * 32 + quad * 8);
        #pragma unroll
        for (int g = 0; g < 4; ++g)
            acc[g] = __builtin_amdgcn_mfma_f32_16x16x32_bf16(
                         afrag, bfrag[kb][g], acc[g], 0, 0, 0);
    }

    // ---- stage results into LDS out-tiles ----
    #pragma unroll
    for (int g = 0; g < 4; ++g) {
        #pragma unroll
        for (int r = 0; r < 4; ++r) {
            const int row = quad * 4 + r;
            const int col = 16 * g + l15;
            if (w == 3)
                sOUT[row * 64 + col] = acc[g][r];
            else if (w == 0)
                sQQ[row * 128 + 2 * col] = (unsigned short)f2bf(acc[g][r]);
            else if (w == 4)
                sQQ[row * 128 + 2 * col + 1] = (unsigned short)f2bf(acc[g][r]);
            else   // by-dim layout: d*4 + h + 2*isV  (d=col&31, h=col>>5)
                sKV[row * 128 + (col & 31) * 4 + (col >> 5) + 2 * (w == 2)] =
                    (unsigned short)f2bf(acc[g][r]);
        }
    }
    __syncthreads();

    // ---- contiguous full-line epilogue: 3 x 4KB block copies ----
    if (tid < 256) {
        ((uint4*)(qq + (size_t)nb * 128))[tid]       = ((const uint4*)sQQ)[tid];
        ((uint4*)(zkv + (size_t)nb * 128))[tid]      = ((const uint4*)sKV)[tid];
        ((float4*)(out + (size_t)nb * OUT_DIM))[tid] = ((const float4*)sOUT)[tid];
    }
}

// ---------------------------------------------------------------------------
// agg_k: r9/r11-verified body VERBATIM. One wave per node, two records per
// iteration via the by-dim zkv layout; DPP half_reduce serves both records
// in one pass per head.
// ---------------------------------------------------------------------------
__global__ __launch_bounds__(256) void agg_k(
    const float2* __restrict__ edata2, const int* __restrict__ base,
    const int* __restrict__ bsum, const int* __restrict__ degA,
    const float* __restrict__ w_time, const float* __restrict__ b_time,
    const unsigned short* __restrict__ qq,
    const unsigned short* __restrict__ zkv,
    const float* __restrict__ We_v, float* __restrict__ out)
{
    __shared__ float recs[4][64];               // epilogue strips only
    const int tid  = threadIdx.x;
    const int w    = tid >> 6;
    const int lane = tid & 63;
    const int h    = lane >> 5;                 // which record of the pair
    const int l31  = lane & 31;                 // dim
    const int n    = blockIdx.x * 4 + w;

    const int b0  = base[n] + bsum[n >> 8];
    const int deg = degA[n];

    const float wt = w_time[l31];
    const float bt = b_time[l31];

    // dst-side q/qek for BOTH heads at this dim, once; fold log2e.
    const unsigned qv0 = *(const unsigned*)(qq + (size_t)n * 128 + 2 * l31);
    const unsigned qv1 = *(const unsigned*)(qq + (size_t)n * 128 + 64 + 2 * l31);
    const float q0  = lo16(qv0) * LOG2E, qe0 = hi16(qv0) * LOG2E;
    const float q1  = lo16(qv1) * LOG2E, qe1 = hi16(qv1) * LOG2E;

    float av0 = 0.f, av1 = 0.f, pte0 = 0.f, pte1 = 0.f, lp0 = 0.f, lp1 = 0.f;

    #define PAIR_COMPUTE(RR, KV, MASKED)                                     \
    {                                                                        \
        const float te = __cosf((RR).y * wt + bt);                           \
        float p0 = q0 * lo16((KV).x) + qe0 * te;                             \
        float p1 = q1 * hi16((KV).x) + qe1 * te;                             \
        p0 = half_reduce(p0);                                                \
        p1 = half_reduce(p1);                                                \
        float pe0 = exp2f(p0), pe1 = exp2f(p1);                              \
        if (MASKED) { if (h) { pe0 = 0.f; pe1 = 0.f; } }                     \
        av0  += pe0 * lo16((KV).y);                                          \
        av1  += pe1 * hi16((KV).y);                                          \
        pte0 += pe0 * te;                                                    \
        pte1 += pe1 * te;                                                    \
        lp0  += pe0;                                                         \
        lp1  += pe1;                                                         \
    }

    const int fp = deg >> 1;                    // full pairs
    int p = 0;
    for (; p + 4 <= fp; p += 4) {               // 4 pairs = 8 records batched
        float2 r[4];
        #pragma unroll
        for (int j = 0; j < 4; ++j) r[j] = edata2[b0 + 2 * (p + j) + h];
        uint2 kv[4];
        #pragma unroll
        for (int j = 0; j < 4; ++j)
            kv[j] = *(const uint2*)((const char*)zkv +
                      (((unsigned)__float_as_int(r[j].x)) << 8) + (l31 << 3));
        #pragma unroll
        for (int j = 0; j < 4; ++j) PAIR_COMPUTE(r[j], kv[j], false)
    }
    for (; p < fp; ++p) {                       // leftover full pairs
        const float2 r = edata2[b0 + 2 * p + h];
        const uint2 kv = *(const uint2*)((const char*)zkv +
                      (((unsigned)__float_as_int(r.x)) << 8) + (l31 << 3));
        PAIR_COMPUTE(r, kv, false)
    }
    if (deg & 1) {                              // odd last record: lower half only
        const float2 r = edata2[b0 + deg - 1];
        const uint2 kv = *(const uint2*)((const char*)zkv +
                      (((unsigned)__float_as_int(r.x)) << 8) + (l31 << 3));
        PAIR_COMPUTE(r, kv, true)
    }
    #undef PAIR_COMPUTE

    // ---- merge halves (even-record sums + odd-record sums) ----
    av0  += __shfl_xor(av0, 32);
    av1  += __shfl_xor(av1, 32);
    pte0 += __shfl_xor(pte0, 32);
    pte1 += __shfl_xor(pte1, 32);
    lp0  += __shfl_xor(lp0, 32);
    lp1  += __shfl_xor(lp1, 32);

    // ---- fused We_v epilogue (rec[h*32+d] = pte[h][d]) ----
    float* rec = &recs[w][0];
    rec[lane] = h ? pte1 : pte0;
    float wev[32];
    #pragma unroll
    for (int k = 0; k < 32; ++k) wev[k] = We_v[k * 64 + lane];

    const float lp  = h ? lp1 : lp0;
    const float av  = h ? av1 : av0;
    const float inv = (lp > 0.f) ? 1.f / lp : 0.f;
    const float4* pv = (const float4*)(rec + h * 32);
    float dot = 0.f;
    #pragma unroll
    for (int k = 0; k < 8; ++k) {
        const float4 c = pv[k];
        dot += c.x * wev[4 * k]     + c.y * wev[4 * k + 1]
             + c.z * wev[4 * k + 2] + c.w * wev[4 * k + 3];
    }

    out[(size_t)n * OUT_DIM + lane] += (av + dot) * inv;   // skip already there
}

extern "C" void kernel_launch(void* const* d_in, const int* in_sizes, int n_in,
                              void* d_out, int out_size, void* d_ws, size_t ws_size,
                              hipStream_t stream) {
    (void)in_sizes; (void)n_in; (void)out_size; (void)ws_size;
    const int*   src    = (const int*)d_in[0];
    const int*   dst    = (const int*)d_in[1];
    const float* t      = (const float*)d_in[2];
    const float* x      = (const float*)d_in[3];
    const float* mem    = (const float*)d_in[4];
    const float* w_time = (const float*)d_in[5];
    const float* b_time = (const float*)d_in[6];
    const float* Wq     = (const float*)d_in[7];
    const float* Wk     = (const float*)d_in[8];
    const float* Wv     = (const float*)d_in[9];
    const float* We_k   = (const float*)d_in[10];
    const float* We_v   = (const float*)d_in[11];
    const float* Wskip  = (const float*)d_in[12];

    // workspace layout (16B-aligned chunks)
    char* p = (char*)d_ws;
    unsigned short* zkv = (unsigned short*)p; p += (size_t)N_NODES * 128 * 2; // 12.8 MB (by-dim k/v)
    unsigned short* qq  = (unsigned short*)p; p += (size_t)N_NODES * 128 * 2; // 12.8 MB (q|qek interleaved)
    unsigned short* wtb = (unsigned short*)p; p += (size_t)5 * 64 * 160 * 2;  // 100 KB
    float2* edata2 = (float2*)p; p += (size_t)N_EDGES * 8;                    // 6.4 MB
    int*  cntr  = (int*)p;   p += (size_t)8 * N_NODES * 4;   // zeroed by memset
    int*  flag  = (int*)p;   p += 16;                        // scan12 counter
    int*  rank  = (int*)p;   p += (size_t)N_EDGES * 4;       // 3.2 MB
    int*  base  = (int*)p;   p += (size_t)N_NODES * 4;
    int*  deg   = (int*)p;   p += (size_t)N_NODES * 4;
    int*  bsum  = (int*)p;   p += 256 * 4;
    float* out  = (float*)d_out;

    hipMemsetAsync(cntr, 0, (size_t)8 * N_NODES * 4 + 16, stream);  // cntr+flag
    prep_hist_k<<<NPREP + 3125, 256, 0, stream>>>(Wq, Wk, Wv, Wskip, We_k, wtb,
                                                  dst, cntr, rank);
    scan12_k <<<NB_SCAN, 256, 0, stream>>>(cntr, base, bsum, deg, flag);
    gemm_scatter_k<<<NGB + 2500, 320, 0, stream>>>(x, mem, wtb, qq, zkv, out,
                                                   src, dst, t, rank, base,
                                                   bsum, cntr, edata2);
    agg_k    <<<N_NODES / 4, 256, 0, stream>>>(edata2, base, bsum, deg,
                                               w_time, b_time, qq, zkv, We_v, out);
}

// Round 13
// 237.555 us; speedup vs baseline: 1.0587x; 1.0070x over previous
//
#include <hip/hip_runtime.h>
#include <hip/hip_bf16.h>
#include <math.h>

#define N_NODES 50000
#define N_EDGES 800000
#define IN_DIM  128
#define MEM_DIM 32
#define OUT_DIM 64
#define NB_SCAN ((N_NODES + 255) / 256)   // 196
#define SCALE   0.17677669529663687f      // 1/sqrt(32)
#define LOG2E   1.44269504088896f
#define LDS_AROW 168                      // padded A-tile row stride (elems)
#define NGB 3125                          // single-tile GEMM blocks (16 nodes each)

typedef __attribute__((ext_vector_type(8))) short bf16x8;
typedef __attribute__((ext_vector_type(4))) float f32x4;

__device__ __forceinline__ short f2bf(float f) {
    union { float f; unsigned u; } v; v.f = f;
    unsigned r = v.u + 0x7FFF + ((v.u >> 16) & 1);   // round-to-nearest-even
    return (short)(r >> 16);
}
__device__ __forceinline__ float lo16(unsigned u) { return __uint_as_float(u << 16); }
__device__ __forceinline__ float hi16(unsigned u) { return __uint_as_float(u & 0xffff0000u); }

// Cross-lane add via DPP (VALU pipe, not LDS). CTRL: 0xB1=quad_perm xor1,
// 0x4E=quad_perm xor2, 0x124=row_ror:4, 0x128=row_ror:8.
template <int CTRL>
__device__ __forceinline__ float dpp_mov(float x) {
    return __int_as_float(__builtin_amdgcn_update_dpp(
        0, __float_as_int(x), CTRL, 0xF, 0xF, true));
}
// xor16 within each 32-lane half (BitMode: xor=16, and=0x1F)
__device__ __forceinline__ float swz16(float x) {
    return __int_as_float(__builtin_amdgcn_ds_swizzle(__float_as_int(x), 0x401F));
}
// sum over the lane's 32-lane half: 4 DPP adds + 1 swizzle. Each 32-lane
// half reduces INDEPENDENTLY (one pass serves 2 records).
__device__ __forceinline__ float half_reduce(float pr) {
    pr += dpp_mov<0xB1>(pr);
    pr += dpp_mov<0x4E>(pr);
    pr += dpp_mov<0x124>(pr);
    pr += dpp_mov<0x128>(pr);
    pr += swz16(pr);
    return pr;
}

// ---------------------------------------------------------------------------
// prep_k: bf16 weight bank in lane-coalesced B-frag layout (r12-verified prep
// branch, standalone; cntr/flag zeroing handled by hipMemsetAsync).
// ---------------------------------------------------------------------------
__global__ __launch_bounds__(256) void prep_k(
    const float* __restrict__ Wq, const float* __restrict__ Wk,
    const float* __restrict__ Wv, const float* __restrict__ Wskip,
    const float* __restrict__ We_k, unsigned short* __restrict__ wtb)
{
    const int i = blockIdx.x * 256 + threadIdx.x;   // 200*256 == 51200 == 5*64*160
    const int m = i / 10240, rem = i % 10240, c = rem / 160, k = rem % 160;
    float v;
    if (m == 4) {
        const int h = c >> 5, kk = c & 31;
        v = 0.f;
        #pragma unroll
        for (int j = 0; j < 32; ++j)
            v += Wq[k * 64 + h * 32 + j] * We_k[kk * 64 + h * 32 + j];
        v *= SCALE;
    } else {
        const float* W = (m == 0) ? Wq : (m == 1) ? Wk : (m == 2) ? Wv : Wskip;
        v = W[k * 64 + c];
        if (m == 0) v *= SCALE;
    }
    const int g = c >> 4, l15 = c & 15;
    const int kb = k >> 5, quad = (k >> 3) & 3, j = k & 7;
    wtb[(size_t)((((m * 5 + kb) * 4 + g) * 64) + quad * 16 + l15) * 8 + j] =
        (unsigned short)f2bf(v);
}

// ---------------------------------------------------------------------------
// gemm_hist_k: the r5-verified pairing, with the r12-verified single-tile
// GEMM body. Blocks [0,NGB): 16-node GEMM (B-frags in registers, LDS A-tile,
// by-dim zkv layout, contiguous-line epilogue). Blocks [NGB,NGB+2500): the
// 8-replica dst histogram + rank capture (320-thread form verified r5;
// replica/rank math is a pure function of the absolute edge id e). The
// MFMA/LDS-heavy GEMM hides the atomic pass's latency.
// ---------------------------------------------------------------------------
__global__ __launch_bounds__(320) void gemm_hist_k(
    const float* __restrict__ x, const float* __restrict__ mem,
    const unsigned short* __restrict__ wtb,
    unsigned short* __restrict__ qq, unsigned short* __restrict__ zkv,
    float* __restrict__ out,
    const int* __restrict__ dst, int* __restrict__ cntr, int* __restrict__ rank)
{
    const int tid = threadIdx.x;
    if (blockIdx.x >= NGB) {
        const int e = (blockIdx.x - NGB) * 320 + tid;   // 2500*320 == E
        rank[e] = atomicAdd(&cntr[((e >> 8) & 7) * N_NODES + dst[e]], 1);
        return;
    }
    __shared__ unsigned short sA[16 * LDS_AROW];    // 5.25 KB bf16 in-tile
    __shared__ unsigned short sQQ[16 * 128];        // 4 KB
    __shared__ unsigned short sKV[16 * 128];        // 4 KB
    __shared__ float          sOUT[16 * 64];        // 4 KB

    const int w    = tid >> 6;                  // 0..4 (matrix id)
    const int lane = tid & 63;
    const int l15  = lane & 15;
    const int quad = lane >> 4;
    const int nb   = blockIdx.x * 16;

    // ---- B-frags: coalesced 1KB loads, L2-resident wtb ----
    bf16x8 bfrag[5][4];
    #pragma unroll
    for (int kb = 0; kb < 5; ++kb)
        #pragma unroll
        for (int g = 0; g < 4; ++g)
            bfrag[kb][g] = *(const bf16x8*)(wtb +
                (size_t)(((w * 5 + kb) * 4 + g) * 64 + lane) * 8);

    // ---- cooperative coalesced stage: x (16x128) + mem (16x32) -> sA ----
    for (int i = tid; i < 640; i += 320) {
        float4 f;
        int row, dim;
        if (i < 512) {                       // x part: 16 rows x 32 float4
            row = i >> 5; dim = (i & 31) * 4;
            f = *(const float4*)(x + (size_t)(nb + row) * IN_DIM + dim);
        } else {                             // mem part: 16 rows x 8 float4
            const int j = i - 512;
            row = j >> 3; dim = 128 + (j & 7) * 4;
            f = *(const float4*)(mem + (size_t)(nb + row) * MEM_DIM + (dim - 128));
        }
        unsigned short* d2 = sA + row * LDS_AROW + dim;
        d2[0] = (unsigned short)f2bf(f.x); d2[1] = (unsigned short)f2bf(f.y);
        d2[2] = (unsigned short)f2bf(f.z); d2[3] = (unsigned short)f2bf(f.w);
    }
    __syncthreads();

    f32x4 acc[4];
    #pragma unroll
    for (int g = 0; g < 4; ++g) acc[g] = (f32x4)0.0f;
    #pragma unroll
    for (int kb = 0; kb < 5; ++kb) {
        const bf16x8 afrag =
            *(const bf16x8*)(sA + l15 * LDS_AROW + kb * 32 + quad * 8);
        #pragma unroll
        for (int g = 0; g < 4; ++g)
            acc[g] = __builtin_amdgcn_mfma_f32_16x16x32_bf16(
                         afrag, bfrag[kb][g], acc[g], 0, 0, 0);
    }

    // ---- stage results into LDS out-tiles ----
    #pragma unroll
    for (int g = 0; g < 4; ++g) {
        #pragma unroll
        for (int r = 0; r < 4; ++r) {
            const int row = quad * 4 + r;
            const int col = 16 * g + l15;
            if (w == 3)
                sOUT[row * 64 + col] = acc[g][r];
            else if (w == 0)
                sQQ[row * 128 + 2 * col] = (unsigned short)f2bf(acc[g][r]);
            else if (w == 4)
                sQQ[row * 128 + 2 * col + 1] = (unsigned short)f2bf(acc[g][r]);
            else   // by-dim layout: d*4 + h + 2*isV  (d=col&31, h=col>>5)
                sKV[row * 128 + (col & 31) * 4 + (col >> 5) + 2 * (w == 2)] =
                    (unsigned short)f2bf(acc[g][r]);
        }
    }
    __syncthreads();

    // ---- contiguous full-line epilogue: 3 x 4KB block copies ----
    if (tid < 256) {
        ((uint4*)(qq + (size_t)nb * 128))[tid]       = ((const uint4*)sQQ)[tid];
        ((uint4*)(zkv + (size_t)nb * 128))[tid]      = ((const uint4*)sKV)[tid];
        ((float4*)(out + (size_t)nb * OUT_DIM))[tid] = ((const float4*)sOUT)[tid];
    }
}

// ---------------------------------------------------------------------------
// scan12_k: r12-verified scan1+scan2 fold (last-block pattern).
// ---------------------------------------------------------------------------
__global__ __launch_bounds__(256) void scan12_k(int* __restrict__ cntr,
                                                int* __restrict__ base,
                                                int* __restrict__ bsum,
                                                int* __restrict__ deg,
                                                int* __restrict__ flag)
{
    __shared__ int sh[256];
    __shared__ int isLast;
    const int i = blockIdx.x * 256 + threadIdx.x;
    int tot = 0;
    if (i < N_NODES) {
        int off = 0;
        #pragma unroll
        for (int r = 0; r < 8; ++r) {
            const int c = cntr[r * N_NODES + i];
            cntr[r * N_NODES + i] = off;
            off += c;
        }
        tot = off;
        deg[i] = tot;
    }
    sh[threadIdx.x] = tot;
    __syncthreads();
    int val = tot;
    for (int off = 1; off < 256; off <<= 1) {
        const int y = (threadIdx.x >= off) ? sh[threadIdx.x - off] : 0;
        __syncthreads();
        val += y; sh[threadIdx.x] = val;
        __syncthreads();
    }
    if (i < N_NODES) base[i] = val - tot;
    if (threadIdx.x == 255) {
        bsum[blockIdx.x] = val;
        __threadfence();                         // publish bsum write
        isLast = (atomicAdd(flag, 1) == NB_SCAN - 1);
    }
    __syncthreads();
    if (!isLast) return;

    __threadfence();                             // acquire
    const int ti = threadIdx.x;
    volatile int* vb = bsum;
    const int v = (ti < NB_SCAN) ? vb[ti] : 0;
    sh[ti] = v;
    __syncthreads();
    int val2 = v;
    for (int off = 1; off < 256; off <<= 1) {
        const int y = (ti >= off) ? sh[ti - off] : 0;
        __syncthreads();
        val2 += y; sh[ti] = val2;
        __syncthreads();
    }
    if (ti < NB_SCAN) bsum[ti] = val2 - v;
}

// ---------------------------------------------------------------------------
// scatter_k: ATOMIC-FREE 8B scatter, standalone (r8-verified body verbatim).
//   pos = base[d] + bsum[d>>8] + cntr[r][d] + rank[e],  r = (e>>8)&7.
// ---------------------------------------------------------------------------
__global__ __launch_bounds__(256) void scatter_k(
    const int* __restrict__ srcA, const int* __restrict__ dstA,
    const float* __restrict__ tA, const int* __restrict__ rank,
    const int* __restrict__ base, const int* __restrict__ bsum,
    const int* __restrict__ cntr, float2* __restrict__ edata2)
{
    const int e = blockIdx.x * 256 + threadIdx.x;   // 3125*256 == E
    const int d = dstA[e];
    const int pos = base[d] + bsum[d >> 8]
                  + cntr[((e >> 8) & 7) * N_NODES + d] + rank[e];
    float2 rc;
    rc.x = __int_as_float(srcA[e]);
    rc.y = tA[e];
    edata2[pos] = rc;
}

// ---------------------------------------------------------------------------
// agg_k: r9/r11/r12-verified body VERBATIM. One wave per node, two records
// per iteration via the by-dim zkv layout; DPP half_reduce serves both
// records in one pass per head.
// ---------------------------------------------------------------------------
__global__ __launch_bounds__(256) void agg_k(
    const float2* __restrict__ edata2, const int* __restrict__ base,
    const int* __restrict__ bsum, const int* __restrict__ degA,
    const float* __restrict__ w_time, const float* __restrict__ b_time,
    const unsigned short* __restrict__ qq,
    const unsigned short* __restrict__ zkv,
    const float* __restrict__ We_v, float* __restrict__ out)
{
    __shared__ float recs[4][64];               // epilogue strips only
    const int tid  = threadIdx.x;
    const int w    = tid >> 6;
    const int lane = tid & 63;
    const int h    = lane >> 5;                 // which record of the pair
    const int l31  = lane & 31;                 // dim
    const int n    = blockIdx.x * 4 + w;

    const int b0  = base[n] + bsum[n >> 8];
    const int deg = degA[n];

    const float wt = w_time[l31];
    const float bt = b_time[l31];

    // dst-side q/qek for BOTH heads at this dim, once; fold log2e.
    const unsigned qv0 = *(const unsigned*)(qq + (size_t)n * 128 + 2 * l31);
    const unsigned qv1 = *(const unsigned*)(qq + (size_t)n * 128 + 64 + 2 * l31);
    const float q0  = lo16(qv0) * LOG2E, qe0 = hi16(qv0) * LOG2E;
    const float q1  = lo16(qv1) * LOG2E, qe1 = hi16(qv1) * LOG2E;

    float av0 = 0.f, av1 = 0.f, pte0 = 0.f, pte1 = 0.f, lp0 = 0.f, lp1 = 0.f;

    #define PAIR_COMPUTE(RR, KV, MASKED)                                     \
    {                                                                        \
        const float te = __cosf((RR).y * wt + bt);                           \
        float p0 = q0 * lo16((KV).x) + qe0 * te;                             \
        float p1 = q1 * hi16((KV).x) + qe1 * te;                             \
        p0 = half_reduce(p0);                                                \
        p1 = half_reduce(p1);                                                \
        float pe0 = exp2f(p0), pe1 = exp2f(p1);                              \
        if (MASKED) { if (h) { pe0 = 0.f; pe1 = 0.f; } }                     \
        av0  += pe0 * lo16((KV).y);                                          \
        av1  += pe1 * hi16((KV).y);                                          \
        pte0 += pe0 * te;                                                    \
        pte1 += pe1 * te;                                                    \
        lp0  += pe0;                                                         \
        lp1  += pe1;                                                         \
    }

    const int fp = deg >> 1;                    // full pairs
    int p = 0;
    for (; p + 4 <= fp; p += 4) {               // 4 pairs = 8 records batched
        float2 r[4];
        #pragma unroll
        for (int j = 0; j < 4; ++j) r[j] = edata2[b0 + 2 * (p + j) + h];
        uint2 kv[4];
        #pragma unroll
        for (int j = 0; j < 4; ++j)
            kv[j] = *(const uint2*)((const char*)zkv +
                      (((unsigned)__float_as_int(r[j].x)) << 8) + (l31 << 3));
        #pragma unroll
        for (int j = 0; j < 4; ++j) PAIR_COMPUTE(r[j], kv[j], false)
    }
    for (; p < fp; ++p) {                       // leftover full pairs
        const float2 r = edata2[b0 + 2 * p + h];
        const uint2 kv = *(const uint2*)((const char*)zkv +
                      (((unsigned)__float_as_int(r.x)) << 8) + (l31 << 3));
        PAIR_COMPUTE(r, kv, false)
    }
    if (deg & 1) {                              // odd last record: lower half only
        const float2 r = edata2[b0 + deg - 1];
        const uint2 kv = *(const uint2*)((const char*)zkv +
                      (((unsigned)__float_as_int(r.x)) << 8) + (l31 << 3));
        PAIR_COMPUTE(r, kv, true)
    }
    #undef PAIR_COMPUTE

    // ---- merge halves (even-record sums + odd-record sums) ----
    av0  += __shfl_xor(av0, 32);
    av1  += __shfl_xor(av1, 32);
    pte0 += __shfl_xor(pte0, 32);
    pte1 += __shfl_xor(pte1, 32);
    lp0  += __shfl_xor(lp0, 32);
    lp1  += __shfl_xor(lp1, 32);

    // ---- fused We_v epilogue (rec[h*32+d] = pte[h][d]) ----
    float* rec = &recs[w][0];
    rec[lane] = h ? pte1 : pte0;
    float wev[32];
    #pragma unroll
    for (int k = 0; k < 32; ++k) wev[k] = We_v[k * 64 + lane];

    const float lp  = h ? lp1 : lp0;
    const float av  = h ? av1 : av0;
    const float inv = (lp > 0.f) ? 1.f / lp : 0.f;
    const float4* pv = (const float4*)(rec + h * 32);
    float dot = 0.f;
    #pragma unroll
    for (int k = 0; k < 8; ++k) {
        const float4 c = pv[k];
        dot += c.x * wev[4 * k]     + c.y * wev[4 * k + 1]
             + c.z * wev[4 * k + 2] + c.w * wev[4 * k + 3];
    }

    out[(size_t)n * OUT_DIM + lane] += (av + dot) * inv;   // skip already there
}

extern "C" void kernel_launch(void* const* d_in, const int* in_sizes, int n_in,
                              void* d_out, int out_size, void* d_ws, size_t ws_size,
                              hipStream_t stream) {
    (void)in_sizes; (void)n_in; (void)out_size; (void)ws_size;
    const int*   src    = (const int*)d_in[0];
    const int*   dst    = (const int*)d_in[1];
    const float* t      = (const float*)d_in[2];
    const float* x      = (const float*)d_in[3];
    const float* mem    = (const float*)d_in[4];
    const float* w_time = (const float*)d_in[5];
    const float* b_time = (const float*)d_in[6];
    const float* Wq     = (const float*)d_in[7];
    const float* Wk     = (const float*)d_in[8];
    const float* Wv     = (const float*)d_in[9];
    const float* We_k   = (const float*)d_in[10];
    const float* We_v   = (const float*)d_in[11];
    const float* Wskip  = (const float*)d_in[12];

    // workspace layout (16B-aligned chunks)
    char* p = (char*)d_ws;
    unsigned short* zkv = (unsigned short*)p; p += (size_t)N_NODES * 128 * 2; // 12.8 MB (by-dim k/v)
    unsigned short* qq  = (unsigned short*)p; p += (size_t)N_NODES * 128 * 2; // 12.8 MB (q|qek interleaved)
    unsigned short* wtb = (unsigned short*)p; p += (size_t)5 * 64 * 160 * 2;  // 100 KB
    float2* edata2 = (float2*)p; p += (size_t)N_EDGES * 8;                    // 6.4 MB
    int*  cntr  = (int*)p;   p += (size_t)8 * N_NODES * 4;   // zeroed by memset
    int*  flag  = (int*)p;   p += 16;                        // scan12 counter
    int*  rank  = (int*)p;   p += (size_t)N_EDGES * 4;       // 3.2 MB
    int*  base  = (int*)p;   p += (size_t)N_NODES * 4;
    int*  deg   = (int*)p;   p += (size_t)N_NODES * 4;
    int*  bsum  = (int*)p;   p += 256 * 4;
    float* out  = (float*)d_out;

    hipMemsetAsync(cntr, 0, (size_t)8 * N_NODES * 4 + 16, stream);  // cntr+flag
    prep_k   <<<200, 256, 0, stream>>>(Wq, Wk, Wv, Wskip, We_k, wtb);
    gemm_hist_k<<<NGB + 2500, 320, 0, stream>>>(x, mem, wtb, qq, zkv, out,
                                                dst, cntr, rank);
    scan12_k <<<NB_SCAN, 256, 0, stream>>>(cntr, base, bsum, deg, flag);
    scatter_k<<<N_EDGES / 256, 256, 0, stream>>>(src, dst, t, rank, base, bsum,
                                                 cntr, edata2);
    agg_k    <<<N_NODES / 4, 256, 0, stream>>>(edata2, base, bsum, deg,
                                               w_time, b_time, qq, zkv, We_v, out);
}